// Round 1
// baseline (93.339 us; speedup 1.0000x reference)
//
#include <hip/hip_runtime.h>
#include <math.h>

#define A_N      5
#define GRID_HW  52
#define NCLS     80
#define CH       85
#define SCORE_T  0.15f
#define IOU_T    0.5f
#define NEGV     (-1e9f)
#define MAXOUT   10

__global__ void init_counter_kernel(int* __restrict__ counter) {
    *counter = 0;
}

// One thread per box: decode + score + compact live boxes into SoA workspace.
__global__ __launch_bounds__(256) void decode_kernel(
    const float* __restrict__ preds,
    const float* __restrict__ anchors,
    float* __restrict__ bymin, float* __restrict__ bxmin,
    float* __restrict__ bymax, float* __restrict__ bxmax,
    float* __restrict__ bscore, float* __restrict__ bcls,
    int* __restrict__ counter, int N, int capacity)
{
    int idx = blockIdx.x * 256 + threadIdx.x;
    if (idx >= N) return;
    const float* p = preds + (size_t)idx * CH;

    float p0 = p[0], p1 = p[1], p2 = p[2], p3 = p[3], p4 = p[4];

    // Online softmax over the 80 class logits: running max m, sum s of exp(x-m),
    // first-occurrence argmax am (strict > keeps the earliest max, matching jnp.argmax).
    float m = p[5];
    float s = 1.0f;
    int   am = 0;
#pragma unroll
    for (int j = 1; j < NCLS; ++j) {
        float x = p[5 + j];
        if (x > m) am = j;
        float mn = fmaxf(m, x);
        s = s * expf(m - mn) + expf(x - mn);
        m = mn;
    }
    float conf  = 1.0f / (1.0f + expf(-p4));
    float score = conf / s;   // conf * max softmax prob

    if (score >= SCORE_T) {
        int a = idx % A_N;
        int t = idx / A_N;
        int w = t % GRID_HW;
        int h = (t / GRID_HW) % GRID_HW;
        const float inv = 1.0f / (float)GRID_HW;
        float cx = (1.0f / (1.0f + expf(-p0)) + (float)w) * inv;
        float cy = (1.0f / (1.0f + expf(-p1)) + (float)h) * inv;
        float bw = expf(p2) * anchors[2 * a]     * inv;
        float bh = expf(p3) * anchors[2 * a + 1] * inv;

        int pos = atomicAdd(counter, 1);
        if (pos < capacity) {
            bymin[pos]  = cy - 0.5f * bh;
            bxmin[pos]  = cx - 0.5f * bw;
            bymax[pos]  = cy + 0.5f * bh;
            bxmax[pos]  = cx + 0.5f * bw;
            bscore[pos] = score;
            bcls[pos]   = (float)am;
        }
    }
}

// Single-block greedy NMS over the compacted live boxes. MAXOUT iterations of
// {block argmax, emit row, suppress IoU > 0.5}. Dead (below-threshold) boxes
// can never be selected nor affect live scores, so operating on the compacted
// set is exactly the reference semantics.
__global__ __launch_bounds__(256) void nms_kernel(
    float* __restrict__ bymin, float* __restrict__ bxmin,
    float* __restrict__ bymax, float* __restrict__ bxmax,
    float* __restrict__ bscore, float* __restrict__ bcls,
    const int* __restrict__ counter, int capacity,
    float* __restrict__ out)
{
    int M = *counter;
    if (M > capacity) M = capacity;

    __shared__ float s_s[256];
    __shared__ int   s_i[256];
    __shared__ float sbox[6];
    __shared__ int   svalid;

    for (int it = 0; it < MAXOUT; ++it) {
        // --- block argmax with first-index tie-break ---
        float bs = -INFINITY;
        int   bi = -1;
        for (int j = (int)threadIdx.x; j < M; j += 256) {
            float sc = bscore[j];
            if (sc > bs || (sc == bs && (unsigned)j < (unsigned)bi)) { bs = sc; bi = j; }
        }
        s_s[threadIdx.x] = bs;
        s_i[threadIdx.x] = bi;
        __syncthreads();
        for (int off = 128; off > 0; off >>= 1) {
            if ((int)threadIdx.x < off) {
                float os = s_s[threadIdx.x + off];
                int   oi = s_i[threadIdx.x + off];
                float cs = s_s[threadIdx.x];
                int   ci = s_i[threadIdx.x];
                if (os > cs || (os == cs && oi >= 0 && (ci < 0 || oi < ci))) {
                    s_s[threadIdx.x] = os;
                    s_i[threadIdx.x] = oi;
                }
            }
            __syncthreads();
        }

        if (threadIdx.x == 0) {
            int   i = s_i[0];
            float s = s_s[0];
            int valid = (i >= 0) && (s > NEGV * 0.5f);
            svalid = valid;
            if (valid) {
                sbox[0] = bymin[i];
                sbox[1] = bxmin[i];
                sbox[2] = bymax[i];
                sbox[3] = bxmax[i];
                sbox[4] = s;
                sbox[5] = bcls[i];
                bscore[i] = NEGV;
            }
        }
        __syncthreads();

        int valid = svalid;
        if (threadIdx.x < 6) {
            out[it * 6 + threadIdx.x] = valid ? sbox[threadIdx.x] : 0.0f;
        }

        if (valid) {
            float a1 = fmaxf(sbox[2] - sbox[0], 0.0f) * fmaxf(sbox[3] - sbox[1], 0.0f);
            for (int j = (int)threadIdx.x; j < M; j += 256) {
                float ty = fmaxf(sbox[0], bymin[j]);
                float tx = fmaxf(sbox[1], bxmin[j]);
                float by = fminf(sbox[2], bymax[j]);
                float bx = fminf(sbox[3], bxmax[j]);
                float inter = fmaxf(by - ty, 0.0f) * fmaxf(bx - tx, 0.0f);
                float a2 = fmaxf(bymax[j] - bymin[j], 0.0f) * fmaxf(bxmax[j] - bxmin[j], 0.0f);
                float iou = inter / (a1 + a2 - inter + 1e-9f);
                if (iou > IOU_T) bscore[j] = NEGV;
            }
        }
        __syncthreads();
    }
}

extern "C" void kernel_launch(void* const* d_in, const int* in_sizes, int n_in,
                              void* d_out, int out_size, void* d_ws, size_t ws_size,
                              hipStream_t stream) {
    (void)n_in; (void)out_size;
    const float* preds   = (const float*)d_in[0];
    const float* anchors = (const float*)d_in[1];
    float* out = (float*)d_out;

    int N = in_sizes[0] / CH;   // 216,320 boxes

    // Workspace layout: [0,64) counter+pad; then 6 SoA float arrays of `capacity`.
    char* ws = (char*)d_ws;
    int* counter = (int*)ws;
    size_t avail = (ws_size > 64) ? (ws_size - 64) : 0;
    long long cap = (long long)(avail / (6 * sizeof(float)));
    if (cap > N) cap = N;
    if (cap < 0) cap = 0;
    int capacity = (int)cap;

    float* bymin  = (float*)(ws + 64);
    float* bxmin  = bymin  + capacity;
    float* bymax  = bxmin  + capacity;
    float* bxmax  = bymax  + capacity;
    float* bscore = bxmax  + capacity;
    float* bcls   = bscore + capacity;

    init_counter_kernel<<<1, 1, 0, stream>>>(counter);
    decode_kernel<<<(N + 255) / 256, 256, 0, stream>>>(
        preds, anchors, bymin, bxmin, bymax, bxmax, bscore, bcls,
        counter, N, capacity);
    nms_kernel<<<1, 256, 0, stream>>>(
        bymin, bxmin, bymax, bxmax, bscore, bcls, counter, capacity, out);
}